// Round 8
// baseline (997.704 us; speedup 1.0000x reference)
//
#include <hip/hip_runtime.h>
#include <hip/hip_bf16.h>
#include <cstdint>
#include <cstddef>

// Problem constants (match reference)
#define BB 16
#define SS 384
#define GG 384
#define NN 768          // S + G
#define DD 128
#define EC 100
#define TT 21
#define NHEADS 4
#define BN (BB*NN)      // 12288
#define BS (BB*SS)      // 6144

typedef float v2f __attribute__((ext_vector_type(2)));

__device__ __forceinline__ float sigf(float x) { return 1.0f / (1.0f + __expf(-x)); }
__device__ __forceinline__ float tanh_fast(float x) {
    // 1 - 2/(exp(2x)+1); exp overflow -> inf -> 1, underflow -> 0 -> -1
    return 1.0f - 2.0f / (__expf(2.0f * x) + 1.0f);
}
__device__ __forceinline__ float wred_max(float v) {
    #pragma unroll
    for (int o = 32; o > 0; o >>= 1) v = fmaxf(v, __shfl_xor(v, o));
    return v;
}
__device__ __forceinline__ float wred_sum(float v) {
    #pragma unroll
    for (int o = 32; o > 0; o >>= 1) v += __shfl_xor(v, o);
    return v;
}

// ---------------------------------------------------------------------------
// xw = emb @ w_ih^T + b for both directions.  Tiled GEMM with char gather.
// ---------------------------------------------------------------------------
__global__ __launch_bounds__(256) void k_xw(
    const int* __restrict__ batch_char, const float* __restrict__ char_table,
    const float* __restrict__ w_ih_f, const float* __restrict__ b_f,
    const float* __restrict__ w_ih_b, const float* __restrict__ b_b,
    float* __restrict__ xw_f, float* __restrict__ xw_b)
{
    __shared__ float At[EC * 68];   // [e][row]
    __shared__ float Bt[EC * 68];   // [e][gate]
    __shared__ int   chs[64];
    const int tid = threadIdx.x;
    const int rt  = blockIdx.x;             // row tile (64 rows of B*S)
    const int ot  = blockIdx.y;             // dir*4 + gate tile
    const int dir = ot >> 2, gt = ot & 3;
    const float* wih  = dir ? w_ih_b : w_ih_f;
    const float* bias = dir ? b_b    : b_f;
    float*       out  = dir ? xw_b   : xw_f;

    if (tid < 64) chs[tid] = batch_char[rt * 64 + tid];
    __syncthreads();
    for (int idx = tid; idx < 64 * EC; idx += 256) {
        int r = idx / EC, e = idx - r * EC;
        At[e * 68 + r] = char_table[(size_t)chs[r] * EC + e];
        Bt[e * 68 + r] = wih[(size_t)(gt * 64 + r) * EC + e];
    }
    __syncthreads();

    const int ty = tid >> 4, tx = tid & 15;
    const int r0 = ty * 4, c0 = tx * 4;
    float acc[4][4] = {};
    #pragma unroll 4
    for (int e = 0; e < EC; ++e) {
        float4 a = *(const float4*)&At[e * 68 + r0];
        float4 bv = *(const float4*)&Bt[e * 68 + c0];
        float av[4] = {a.x, a.y, a.z, a.w};
        float bb[4] = {bv.x, bv.y, bv.z, bv.w};
        #pragma unroll
        for (int i = 0; i < 4; ++i)
            #pragma unroll
            for (int j = 0; j < 4; ++j) acc[i][j] = fmaf(av[i], bb[j], acc[i][j]);
    }
    #pragma unroll
    for (int i = 0; i < 4; ++i) {
        int row = rt * 64 + r0 + i;
        int gc  = gt * 64 + c0;
        float4 o;
        o.x = acc[i][0] + bias[gc + 0];
        o.y = acc[i][1] + bias[gc + 1];
        o.z = acc[i][2] + bias[gc + 2];
        o.w = acc[i][3] + bias[gc + 3];
        *(float4*)&out[(size_t)row * 256 + gc] = o;
    }
}

// ---------------------------------------------------------------------------
// gaz embedding gather into gat_in rows [S, N)
// ---------------------------------------------------------------------------
__global__ __launch_bounds__(256) void k_gaz(
    const int* __restrict__ gaz_list, const float* __restrict__ gaz_table,
    float* __restrict__ gat_in)
{
    int idx = blockIdx.x * 256 + threadIdx.x;      // B*G*128 total
    int d = idx & 127;
    int rest = idx >> 7;
    int g = rest % GG;
    int b = rest / GG;
    float v = gaz_table[(size_t)gaz_list[b * GG + g] * DD + d];
    gat_in[((size_t)b * NN + SS + g) * DD + d] = v;
}

// ---------------------------------------------------------------------------
// BiLSTM scan.  grid 32 = (batch, dir), 256 threads = 4 waves, j-split.
// KEY CHANGES vs R6 (202us):
//  (1) xw is register-blocked 16 steps ahead (64 VGPRs) -> 15/16 per-step
//      barriers have NO outstanding vmem (s_waitcnt vmcnt(0) precedes every
//      s_barrier; per-step prefetch loads were being drained EVERY step).
//  (2) hbuf LDS round-trip replaced by __shfl: all lanes compute the full
//      identical nh vector, so wave wv's j-chunk h[16wv..16wv+16) lives in
//      its own lanes -> shfl (~30cyc) instead of LDS RAW (~120cyc).
//  h output still banked in hchunk ring, flushed every 32 steps.
// ---------------------------------------------------------------------------
__global__ __launch_bounds__(256, 1) void k_lstm(
    const float* __restrict__ xw_f, const float* __restrict__ xw_b,
    const float* __restrict__ w_hh_f, const float* __restrict__ w_hh_b,
    float* __restrict__ gat_in)
{
    __shared__ float part[2][4][64][4];   // [buf][wave][unit][gate]
    __shared__ float hchunk[32][64];      // h history ring (flush every 32)
    const int tid = threadIdx.x, wv = tid >> 6, lane = tid & 63;
    const int b = blockIdx.x >> 1, dir = blockIdx.x & 1;
    const float* xw  = (dir ? xw_b : xw_f) + (size_t)b * SS * 256;
    const float* whh = dir ? w_hh_b : w_hh_f;
    // weights: gates g*64+lane (unit=lane), j in [16*wv, 16*wv+16)
    v2f w2[4][8];
    #pragma unroll
    for (int g = 0; g < 4; ++g) {
        const float* r = whh + (size_t)(g * 64 + lane) * 64 + 16 * wv;
        #pragma unroll
        for (int jj = 0; jj < 8; ++jj) w2[g][jj] = v2f{r[2 * jj], r[2 * jj + 1]};
    }
    float c = 0.f;
    float nh = 0.f;
    int buf = 0;
    // first step's partial = 0 (h0 = 0)
    *(float4*)part[0][wv][lane] = make_float4(0.f, 0.f, 0.f, 0.f);
    const int jbase = 16 * wv;
    float xr[16][4];                      // 16-step xw register block
    for (int cc = 0; cc < SS / 16; ++cc) {
        // batched coalesced loads; drained once at this chunk's first barrier
        #pragma unroll
        for (int st = 0; st < 16; ++st) {
            const int tt = cc * 16 + st;
            const int t = dir ? (SS - 1 - tt) : tt;
            #pragma unroll
            for (int g = 0; g < 4; ++g)
                xr[st][g] = xw[t * 256 + g * 64 + lane];
        }
        #pragma unroll
        for (int st = 0; st < 16; ++st) {
            const int tt = cc * 16 + st;
            __syncthreads();              // part[buf] now visible; no vmem out
            float4 p0 = *(const float4*)part[buf][0][lane];
            float4 p1 = *(const float4*)part[buf][1][lane];
            float4 p2 = *(const float4*)part[buf][2][lane];
            float4 p3 = *(const float4*)part[buf][3][lane];
            float gi = ((p0.x + p1.x) + (p2.x + p3.x)) + xr[st][0];
            float gf = ((p0.y + p1.y) + (p2.y + p3.y)) + xr[st][1];
            float gg = ((p0.z + p1.z) + (p2.z + p3.z)) + xr[st][2];
            float go = ((p0.w + p1.w) + (p2.w + p3.w)) + xr[st][3];
            float nc = sigf(gf) * c + sigf(gi) * tanh_fast(gg);
            nh = sigf(go) * tanh_fast(nc);
            c = nc;
            if (wv == 0) hchunk[tt & 31][lane] = nh;
            // partial matvec for NEXT step: own-lane h chunk via shfl
            v2f a0 = v2f{0.f, 0.f}, a1 = v2f{0.f, 0.f}, a2 = v2f{0.f, 0.f}, a3 = v2f{0.f, 0.f};
            #pragma unroll
            for (int jj = 0; jj < 8; ++jj) {
                v2f hv = v2f{__shfl(nh, jbase + 2 * jj), __shfl(nh, jbase + 2 * jj + 1)};
                a0 = __builtin_elementwise_fma(hv, w2[0][jj], a0);
                a1 = __builtin_elementwise_fma(hv, w2[1][jj], a1);
                a2 = __builtin_elementwise_fma(hv, w2[2][jj], a2);
                a3 = __builtin_elementwise_fma(hv, w2[3][jj], a3);
            }
            float4 pw;
            pw.x = a0.x + a0.y; pw.y = a1.x + a1.y;
            pw.z = a2.x + a2.y; pw.w = a3.x + a3.y;
            *(float4*)part[buf ^ 1][wv][lane] = pw;
            buf ^= 1;
            if ((tt & 31) == 31) {        // flush 32 h rows (off critical path)
                __syncthreads();
                const int c0 = tt & ~31;
                #pragma unroll
                for (int r = 0; r < 8; ++r) {
                    const int rr = wv + 4 * r;
                    const int tr = dir ? (SS - 1 - (c0 + rr)) : (c0 + rr);
                    gat_in[((size_t)b * NN + tr) * DD + dir * 64 + lane] = hchunk[rr][lane];
                }
            }
        }
    }
}

// ---------------------------------------------------------------------------
// GAT layer-1 projection: h1 = gat_in @ Wh[k][hd] (+ per-row f1/f2 dots).
// ---------------------------------------------------------------------------
__global__ __launch_bounds__(256) void k_p1(
    const float* __restrict__ gat_in, const float* __restrict__ gat_Wh,
    const float* __restrict__ gat_ah, int k,
    float* __restrict__ h1, float* __restrict__ f1g, float* __restrict__ f2g)
{
    __shared__ float At[64 * 68];
    __shared__ float Bt[64 * 68];
    __shared__ float sf1[64], sf2[64];
    const int tid = threadIdx.x;
    const int rt = blockIdx.x, hd = blockIdx.y;
    if (tid < 64) { sf1[tid] = 0.f; sf2[tid] = 0.f; }
    const float* W = gat_Wh + ((size_t)(k * NHEADS + hd)) * DD * 64;
    const int ty = tid >> 4, tx = tid & 15;
    const int r0 = ty * 4, c0 = tx * 4;
    float acc[4][4] = {};
    for (int ph = 0; ph < 2; ++ph) {
        __syncthreads();
        for (int idx = tid; idx < 64 * 64; idx += 256) {
            int r = idx >> 6, e = idx & 63;
            At[e * 68 + r] = gat_in[((size_t)(rt * 64 + r)) * DD + ph * 64 + e];
            Bt[e * 68 + r] = W[(size_t)(ph * 64 + e) * 64 + r];
        }
        __syncthreads();
        #pragma unroll 4
        for (int e = 0; e < 64; ++e) {
            float4 a = *(const float4*)&At[e * 68 + r0];
            float4 bv = *(const float4*)&Bt[e * 68 + c0];
            float av[4] = {a.x, a.y, a.z, a.w};
            float bb[4] = {bv.x, bv.y, bv.z, bv.w};
            #pragma unroll
            for (int i = 0; i < 4; ++i)
                #pragma unroll
                for (int j = 0; j < 4; ++j) acc[i][j] = fmaf(av[i], bb[j], acc[i][j]);
        }
    }
    const float* ah = gat_ah + (size_t)(k * NHEADS + hd) * 128;
    float a1[4], a2[4];
    #pragma unroll
    for (int j = 0; j < 4; ++j) { a1[j] = ah[c0 + j]; a2[j] = ah[64 + c0 + j]; }
    #pragma unroll
    for (int i = 0; i < 4; ++i) {
        int n = rt * 64 + r0 + i;
        float4 o = make_float4(acc[i][0], acc[i][1], acc[i][2], acc[i][3]);
        *(float4*)&h1[((size_t)n * NHEADS + hd) * 64 + c0] = o;
        float p1 = acc[i][0] * a1[0] + acc[i][1] * a1[1] + acc[i][2] * a1[2] + acc[i][3] * a1[3];
        float p2 = acc[i][0] * a2[0] + acc[i][1] * a2[1] + acc[i][2] * a2[2] + acc[i][3] * a2[3];
        atomicAdd(&sf1[r0 + i], p1);
        atomicAdd(&sf2[r0 + i], p2);
    }
    __syncthreads();
    if (tid < 64) {
        f1g[hd * BN + rt * 64 + tid] = sf1[tid];
        f2g[hd * BN + rt * 64 + tid] = sf2[tid];
    }
}

// ---------------------------------------------------------------------------
// GAT layer-1 attention (sparse).  One block per row n=(b,i); wave = head.
// ---------------------------------------------------------------------------
__global__ __launch_bounds__(256) void k_attn1(
    const int* __restrict__ adj, const float* __restrict__ h1,
    const float* __restrict__ f1g, const float* __restrict__ f2g,
    float* __restrict__ out1, unsigned long long* __restrict__ packed)
{
    __shared__ int   nbr[NN];
    __shared__ float ep[NHEADS][NN];
    __shared__ unsigned long long wm[12];
    __shared__ int cntS;
    const int tid = threadIdx.x, wave = tid >> 6, lane = tid & 63;
    const int n = blockIdx.x;
    const int b = n / NN;
    #pragma unroll
    for (int it = 0; it < 3; ++it) {
        int j = it * 256 + tid;
        int a = adj[(size_t)n * NN + j];
        unsigned long long m = __ballot(a > 0);
        if (lane == 0) { wm[it * 4 + wave] = m; packed[(size_t)n * 12 + it * 4 + wave] = m; }
    }
    __syncthreads();
    if (wave == 0) {
        unsigned long long m = (lane < 12) ? wm[lane] : 0ULL;
        int pc = __popcll(m);
        int inc = pc;
        #pragma unroll
        for (int d = 1; d < 16; d <<= 1) { int t = __shfl_up(inc, d); if (lane >= d) inc += t; }
        int C = __shfl(inc, 11);
        if (lane == 0) cntS = C;
        int off = inc - pc;
        while (m) {
            int bit = __builtin_ctzll(m);
            nbr[off++] = lane * 64 + bit;
            m &= m - 1;
        }
    }
    __syncthreads();
    const int C = cntS;
    const int hd = wave;
    const float f1 = f1g[hd * BN + n];
    const float* f2p = f2g + hd * BN + b * NN;
    float mx = -3.0e38f;
    for (int t = lane; t < C; t += 64) {
        float e = f1 + f2p[nbr[t]];
        e = (e >= 0.f) ? e : 0.2f * e;
        ep[hd][t] = e;
        mx = fmaxf(mx, e);
    }
    mx = wred_max(mx);
    float sum = 0.f;
    for (int t = lane; t < C; t += 64) {
        float p = __expf(ep[hd][t] - mx);
        ep[hd][t] = p;
        sum += p;
    }
    sum = wred_sum(sum);
    const float* hb = h1 + (size_t)b * NN * (NHEADS * 64) + hd * 64 + lane;
    float ac0 = 0.f, ac1 = 0.f, ac2 = 0.f, ac3 = 0.f;
    int t = 0;
    for (; t + 3 < C; t += 4) {
        int j0 = nbr[t], j1 = nbr[t + 1], j2 = nbr[t + 2], j3 = nbr[t + 3];
        float p0 = ep[hd][t], p1 = ep[hd][t + 1], p2 = ep[hd][t + 2], p3 = ep[hd][t + 3];
        ac0 = fmaf(p0, hb[(size_t)j0 * 256], ac0);
        ac1 = fmaf(p1, hb[(size_t)j1 * 256], ac1);
        ac2 = fmaf(p2, hb[(size_t)j2 * 256], ac2);
        ac3 = fmaf(p3, hb[(size_t)j3 * 256], ac3);
    }
    for (; t < C; ++t) ac0 = fmaf(ep[hd][t], hb[(size_t)nbr[t] * 256], ac0);
    float r = ((ac0 + ac1) + (ac2 + ac3)) / sum;
    r = (r > 0.f) ? r : expm1f(r);
    out1[(size_t)n * 256 + hd * 64 + lane] = r;
}

// ---------------------------------------------------------------------------
// Output-layer projection: h2 = out1 @ Wo[k]  (+ f1o/f2o dots).  12 rows/block.
// ---------------------------------------------------------------------------
__global__ __launch_bounds__(256) void k_p2(
    const float* __restrict__ out1, const float* __restrict__ gat_Wo,
    const float* __restrict__ gat_ao, int k,
    float* __restrict__ h2, float* __restrict__ f1o, float* __restrict__ f2o)
{
    __shared__ float ld[12 * 256];
    __shared__ float lf1[12], lf2[12];
    const int tid = threadIdx.x;
    const int blk = blockIdx.x;
    if (tid < 12) { lf1[tid] = 0.f; lf2[tid] = 0.f; }
    for (int idx = tid; idx < 12 * 256; idx += 256)
        ld[idx] = out1[(size_t)blk * 12 * 256 + idx];
    __syncthreads();
    if (tid < 252) {
        const int r = tid / TT, c = tid - r * TT;
        const float* Wo = gat_Wo + (size_t)k * 256 * TT;
        const float4* row4 = (const float4*)&ld[r * 256];
        float acc = 0.f;
        #pragma unroll 8
        for (int q4 = 0; q4 < 64; ++q4) {
            float4 v = row4[q4];
            int q = q4 * 4;
            acc = fmaf(v.x, Wo[(q + 0) * TT + c], acc);
            acc = fmaf(v.y, Wo[(q + 1) * TT + c], acc);
            acc = fmaf(v.z, Wo[(q + 2) * TT + c], acc);
            acc = fmaf(v.w, Wo[(q + 3) * TT + c], acc);
        }
        const int n = blk * 12 + r;
        h2[(size_t)n * TT + c] = acc;
        const float* ao = gat_ao + k * 2 * TT;
        atomicAdd(&lf1[r], acc * ao[c]);
        atomicAdd(&lf2[r], acc * ao[TT + c]);
    }
    __syncthreads();
    if (tid < 12) {
        f1o[blk * 12 + tid] = lf1[tid];
        f2o[blk * 12 + tid] = lf2[tid];
    }
}

// ---------------------------------------------------------------------------
// Output-layer attention + elu.  One wave per (b, s<S).
// ---------------------------------------------------------------------------
__global__ __launch_bounds__(64) void k_attn2(
    const unsigned long long* __restrict__ packed,
    const float* __restrict__ h2, const float* __restrict__ f1o,
    const float* __restrict__ f2o, float* __restrict__ out2k)
{
    __shared__ int   nbr[NN];
    __shared__ float ep[NN];
    const int lane = threadIdx.x;
    const int blk = blockIdx.x;                 // b*S + s
    const int b = blk / SS, s = blk - b * SS;
    const int n = b * NN + s;
    unsigned long long w64 = (lane < 12) ? packed[(size_t)n * 12 + lane] : 0ULL;
    int pc = __popcll(w64);
    int inc = pc;
    #pragma unroll
    for (int d = 1; d < 16; d <<= 1) {
        int t = __shfl_up(inc, d, 16);
        if ((lane & 15) >= d) inc += t;
    }
    const int C = __shfl(inc, 11);
    int off = inc - pc;
    while (w64) {
        int bit = __builtin_ctzll(w64);
        nbr[off++] = lane * 64 + bit;
        w64 &= w64 - 1;
    }
    __syncthreads();
    const float f1 = f1o[n];
    const float* f2p = f2o + b * NN;
    float mx = -3.0e38f;
    for (int t = lane; t < C; t += 64) {
        int j = nbr[t];
        float e = f1 + f2p[j];
        e = (e >= 0.f) ? e : 0.2f * e;
        ep[t] = e;
        mx = fmaxf(mx, e);
    }
    mx = wred_max(mx);
    float sum = 0.f;
    for (int t = lane; t < C; t += 64) {
        float p = __expf(ep[t] - mx);
        ep[t] = p;
        sum += p;
    }
    sum = wred_sum(sum);
    const float* h2b = h2 + (size_t)b * NN * TT + ((lane < TT) ? lane : 0);
    float ac0 = 0.f, ac1 = 0.f, ac2 = 0.f, ac3 = 0.f;
    int t = 0;
    for (; t + 3 < C; t += 4) {
        int j0 = nbr[t], j1 = nbr[t + 1], j2 = nbr[t + 2], j3 = nbr[t + 3];
        float p0 = ep[t], p1 = ep[t + 1], p2 = ep[t + 2], p3 = ep[t + 3];
        ac0 = fmaf(p0, h2b[(size_t)j0 * TT], ac0);
        ac1 = fmaf(p1, h2b[(size_t)j1 * TT], ac1);
        ac2 = fmaf(p2, h2b[(size_t)j2 * TT], ac2);
        ac3 = fmaf(p3, h2b[(size_t)j3 * TT], ac3);
    }
    for (; t < C; ++t) ac0 = fmaf(ep[t], h2b[(size_t)nbr[t] * TT], ac0);
    if (lane < TT) {
        float r = ((ac0 + ac1) + (ac2 + ac3)) / sum;
        r = (r > 0.f) ? r : expm1f(r);
        out2k[(size_t)blk * TT + lane] = r;
    }
}

// ---------------------------------------------------------------------------
// feats = fuse_w[0]*(lstm_feat@h2h_W^T + b) + sum_k fuse_w[k+1]*out2_k
// ---------------------------------------------------------------------------
__global__ __launch_bounds__(64) void k_fuse(
    const float* __restrict__ gat_in, const float* __restrict__ h2h_W,
    const float* __restrict__ h2h_b, const float* __restrict__ fuse_w,
    const float* __restrict__ out2, float* __restrict__ feats)
{
    __shared__ float row[DD];
    const int lane = threadIdx.x;
    const int blk = blockIdx.x;                 // b*S + s
    const int b = blk / SS, s = blk - b * SS;
    const float* src = gat_in + ((size_t)b * NN + s) * DD;
    row[lane] = src[lane];
    row[lane + 64] = src[lane + 64];
    __syncthreads();
    if (lane < TT) {
        float acc = h2h_b[lane];
        const float4* w4 = (const float4*)&h2h_W[lane * DD];
        const float4* r4 = (const float4*)row;
        #pragma unroll 8
        for (int d4 = 0; d4 < 32; ++d4) {
            float4 w = w4[d4]; float4 v = r4[d4];
            acc = fmaf(w.x, v.x, acc); acc = fmaf(w.y, v.y, acc);
            acc = fmaf(w.z, v.z, acc); acc = fmaf(w.w, v.w, acc);
        }
        size_t o = (size_t)blk * TT + lane;
        feats[o] = fuse_w[0] * acc + fuse_w[1] * out2[o]
                 + fuse_w[2] * out2[(size_t)BS * TT + o]
                 + fuse_w[3] * out2[2 * (size_t)BS * TT + o];
    }
}

// ---------------------------------------------------------------------------
// Viterbi decode.  256 threads stage feats row (32KB LDS) coalesced; wave 0
// then runs a barrier-free shfl-only scan and a pipelined shfl backtrace.
// ---------------------------------------------------------------------------
__global__ __launch_bounds__(256) void k_vit(
    const float* __restrict__ feats, const float* __restrict__ trans,
    int* __restrict__ out)
{
    __shared__ float sfeat[SS * TT];            // 8064 floats = 32.25 KB
    __shared__ unsigned char bp[(SS - 1) * 24]; // 9.2 KB
    const int tid = threadIdx.x;
    const int b = blockIdx.x;
    // stage feats[b] coalesced as float4 (8064 = 2016 float4)
    {
        const float4* src = (const float4*)(feats + (size_t)b * SS * TT);
        float4* dst = (float4*)sfeat;
        #pragma unroll
        for (int i = 0; i < 8; ++i) {
            int idx = i * 256 + tid;
            if (idx < 2016) dst[idx] = src[idx];
        }
    }
    __syncthreads();
    if (tid >= 64) return;                      // wave 0 runs the scan
    const int lane = tid;
    const int pg = lane / TT;                   // 0,1,2 (lane 63 idle)
    const int c = lane - pg * TT;
    const bool act = (pg < 3);
    const int p0 = pg * 7;
    float tc[7];
    if (act) {
        #pragma unroll
        for (int u = 0; u < 7; ++u) tc[u] = trans[(p0 + u) * TT + c];
    }
    const float tr_stop = (lane < TT) ? trans[lane * TT + 20] : 0.f;
    // part in registers on lanes 0..20
    float pp = (lane < TT) ? (sfeat[lane] + trans[19 * TT + lane]) : -3.0e38f;
    const int sfl = (lane < TT) ? lane : 0;
    for (int t = 1; t < SS; ++t) {
        float sf = sfeat[t * TT + sfl];         // off critical path
        float best = -3.0e38f; int bi = 0;
        #pragma unroll
        for (int u = 0; u < 7; ++u) {
            float pu = __shfl(pp, p0 + u);      // sources are lanes 0..20
            float v = pu + tc[u];
            if (act && v > best) { best = v; bi = p0 + u; }
        }
        float bv1 = __shfl(best, lane + 21);
        int   bi1 = __shfl(bi,   lane + 21);
        float bv2 = __shfl(best, lane + 42);
        int   bi2 = __shfl(bi,   lane + 42);
        if (lane < TT) {
            if (bv1 > best) { best = bv1; bi = bi1; }
            if (bv2 > best) { best = bv2; bi = bi2; }
            bp[(t - 1) * 24 + lane] = (unsigned char)bi;
            pp = best + sf;
        }
    }
    // final argmax (first-index tie-break)
    float fv = (lane < TT) ? pp + tr_stop : -3.0e38f;
    int fi = (lane < TT) ? lane : 0;
    #pragma unroll
    for (int o = 32; o > 0; o >>= 1) {
        float ov = __shfl_xor(fv, o);
        int oi = __shfl_xor(fi, o);
        if (ov > fv || (ov == fv && oi < fi)) { fv = ov; fi = oi; }
    }
    // pipelined backtrace: all lanes hold row u's 21 bytes; shfl picks [cur]
    int cur = fi;
    if (lane == 0) out[b * SS + SS - 1] = cur;
    int r = (lane < TT) ? (int)bp[(SS - 2) * 24 + lane] : 0;
    for (int u = SS - 2; u >= 0; --u) {
        int rn = 0;
        if (u > 0 && lane < TT) rn = (int)bp[(u - 1) * 24 + lane];  // prefetch
        cur = __shfl(r, cur);
        if (lane == 0) out[b * SS + u] = cur;
        r = rn;
    }
}

// ---------------------------------------------------------------------------
extern "C" void kernel_launch(void* const* d_in, const int* in_sizes, int n_in,
                              void* d_out, int out_size, void* d_ws, size_t ws_size,
                              hipStream_t stream) {
    (void)in_sizes; (void)n_in; (void)out_size; (void)ws_size;
    const int*   batch_char = (const int*)d_in[0];
    const int*   gaz_list   = (const int*)d_in[2];
    const int*   graphs[3]  = {(const int*)d_in[3], (const int*)d_in[4], (const int*)d_in[5]};
    const float* char_table = (const float*)d_in[7];
    const float* gaz_table  = (const float*)d_in[8];
    const float* w_ih_f = (const float*)d_in[9];
    const float* w_hh_f = (const float*)d_in[10];
    const float* b_f    = (const float*)d_in[11];
    const float* w_ih_b = (const float*)d_in[12];
    const float* w_hh_b = (const float*)d_in[13];
    const float* b_b    = (const float*)d_in[14];
    const float* h2h_W  = (const float*)d_in[15];
    const float* h2h_b  = (const float*)d_in[16];
    const float* gat_Wh = (const float*)d_in[17];
    const float* gat_ah = (const float*)d_in[18];
    const float* gat_Wo = (const float*)d_in[19];
    const float* gat_ao = (const float*)d_in[20];
    const float* fuse_w = (const float*)d_in[21];
    const float* trans  = (const float*)d_in[22];

    float* ws = (float*)d_ws;
    float* gat_in = ws;                         // 1,572,864
    float* xw_f   = gat_in + 1572864;           // 1,572,864
    float* xw_b   = xw_f   + 1572864;           // 1,572,864
    float* h1     = xw_b   + 1572864;           // 3,145,728
    float* out1   = h1     + 3145728;           // 3,145,728
    float* h2     = out1   + 3145728;           //   258,048
    float* f1g    = h2     + 258048;            //    49,152
    float* f2g    = f1g    + 49152;             //    49,152
    float* f1o    = f2g    + 49152;             //    12,288
    float* f2o    = f1o    + 12288;             //    12,288
    float* out2   = f2o    + 12288;             //   387,072
    float* feats  = out2   + 387072;            //   129,024
    unsigned long long* packed = (unsigned long long*)(feats + 129024);  // 98,304 u64

    k_xw<<<dim3(96, 8), 256, 0, stream>>>(batch_char, char_table, w_ih_f, b_f,
                                          w_ih_b, b_b, xw_f, xw_b);
    k_gaz<<<3072, 256, 0, stream>>>(gaz_list, gaz_table, gat_in);
    k_lstm<<<32, 256, 0, stream>>>(xw_f, xw_b, w_hh_f, w_hh_b, gat_in);
    for (int k = 0; k < 3; ++k) {
        k_p1<<<dim3(192, 4), 256, 0, stream>>>(gat_in, gat_Wh, gat_ah, k, h1, f1g, f2g);
        k_attn1<<<BN, 256, 0, stream>>>(graphs[k], h1, f1g, f2g, out1, packed);
        k_p2<<<1024, 256, 0, stream>>>(out1, gat_Wo, gat_ao, k, h2, f1o, f2o);
        k_attn2<<<BS, 64, 0, stream>>>(packed, h2, f1o, f2o, out2 + (size_t)k * BS * TT);
    }
    k_fuse<<<BS, 64, 0, stream>>>(gat_in, h2h_W, h2h_b, fuse_w, out2, feats);
    k_vit<<<BB, 256, 0, stream>>>(feats, trans, (int*)d_out);
}

// Round 9
// 972.439 us; speedup vs baseline: 1.0260x; 1.0260x over previous
//
#include <hip/hip_runtime.h>
#include <hip/hip_bf16.h>
#include <cstdint>
#include <cstddef>

// Problem constants (match reference)
#define BB 16
#define SS 384
#define GG 384
#define NN 768          // S + G
#define DD 128
#define EC 100
#define TT 21
#define NHEADS 4
#define BN (BB*NN)      // 12288
#define BS (BB*SS)      // 6144

typedef float v2f __attribute__((ext_vector_type(2)));

__device__ __forceinline__ float sigf(float x) { return 1.0f / (1.0f + __expf(-x)); }
__device__ __forceinline__ float tanh_fast(float x) {
    // 1 - 2/(exp(2x)+1); exp overflow -> inf -> 1, underflow -> 0 -> -1
    return 1.0f - 2.0f / (__expf(2.0f * x) + 1.0f);
}
__device__ __forceinline__ float wred_max(float v) {
    #pragma unroll
    for (int o = 32; o > 0; o >>= 1) v = fmaxf(v, __shfl_xor(v, o));
    return v;
}
__device__ __forceinline__ float wred_sum(float v) {
    #pragma unroll
    for (int o = 32; o > 0; o >>= 1) v += __shfl_xor(v, o);
    return v;
}

// ---------------------------------------------------------------------------
// xw = emb @ w_ih^T + b for both directions.  Tiled GEMM with char gather.
// ---------------------------------------------------------------------------
__global__ __launch_bounds__(256) void k_xw(
    const int* __restrict__ batch_char, const float* __restrict__ char_table,
    const float* __restrict__ w_ih_f, const float* __restrict__ b_f,
    const float* __restrict__ w_ih_b, const float* __restrict__ b_b,
    float* __restrict__ xw_f, float* __restrict__ xw_b)
{
    __shared__ float At[EC * 68];   // [e][row]
    __shared__ float Bt[EC * 68];   // [e][gate]
    __shared__ int   chs[64];
    const int tid = threadIdx.x;
    const int rt  = blockIdx.x;             // row tile (64 rows of B*S)
    const int ot  = blockIdx.y;             // dir*4 + gate tile
    const int dir = ot >> 2, gt = ot & 3;
    const float* wih  = dir ? w_ih_b : w_ih_f;
    const float* bias = dir ? b_b    : b_f;
    float*       out  = dir ? xw_b   : xw_f;

    if (tid < 64) chs[tid] = batch_char[rt * 64 + tid];
    __syncthreads();
    for (int idx = tid; idx < 64 * EC; idx += 256) {
        int r = idx / EC, e = idx - r * EC;
        At[e * 68 + r] = char_table[(size_t)chs[r] * EC + e];
        Bt[e * 68 + r] = wih[(size_t)(gt * 64 + r) * EC + e];
    }
    __syncthreads();

    const int ty = tid >> 4, tx = tid & 15;
    const int r0 = ty * 4, c0 = tx * 4;
    float acc[4][4] = {};
    #pragma unroll 4
    for (int e = 0; e < EC; ++e) {
        float4 a = *(const float4*)&At[e * 68 + r0];
        float4 bv = *(const float4*)&Bt[e * 68 + c0];
        float av[4] = {a.x, a.y, a.z, a.w};
        float bb[4] = {bv.x, bv.y, bv.z, bv.w};
        #pragma unroll
        for (int i = 0; i < 4; ++i)
            #pragma unroll
            for (int j = 0; j < 4; ++j) acc[i][j] = fmaf(av[i], bb[j], acc[i][j]);
    }
    #pragma unroll
    for (int i = 0; i < 4; ++i) {
        int row = rt * 64 + r0 + i;
        int gc  = gt * 64 + c0;
        float4 o;
        o.x = acc[i][0] + bias[gc + 0];
        o.y = acc[i][1] + bias[gc + 1];
        o.z = acc[i][2] + bias[gc + 2];
        o.w = acc[i][3] + bias[gc + 3];
        *(float4*)&out[(size_t)row * 256 + gc] = o;
    }
}

// ---------------------------------------------------------------------------
// gaz embedding gather into gat_in rows [S, N)
// ---------------------------------------------------------------------------
__global__ __launch_bounds__(256) void k_gaz(
    const int* __restrict__ gaz_list, const float* __restrict__ gaz_table,
    float* __restrict__ gat_in)
{
    int idx = blockIdx.x * 256 + threadIdx.x;      // B*G*128 total
    int d = idx & 127;
    int rest = idx >> 7;
    int g = rest % GG;
    int b = rest / GG;
    float v = gaz_table[(size_t)gaz_list[b * GG + g] * DD + d];
    gat_in[((size_t)b * NN + SS + g) * DD + d] = v;
}

// ---------------------------------------------------------------------------
// BiLSTM scan.  EXACT R3 structure (best measured: 199us).  grid 32 =
// (batch, dir), 256 threads, 4-wave j-split, redundant nonlinearity, one
// barrier/step.  Seven variants bracketed this as the latency floor.
// ---------------------------------------------------------------------------
__global__ __launch_bounds__(256) void k_lstm(
    const float* __restrict__ xw_f, const float* __restrict__ xw_b,
    const float* __restrict__ w_hh_f, const float* __restrict__ w_hh_b,
    float* __restrict__ gat_in)
{
    __shared__ float part[2][4][64][4];   // [buf][wave][unit][g4]
    __shared__ float hbuf[4][64];         // per-wave private copy of h
    const int tid = threadIdx.x, wv = tid >> 6, lane = tid & 63;
    const int b = blockIdx.x >> 1, dir = blockIdx.x & 1;
    const float* xw  = (dir ? xw_b : xw_f) + (size_t)b * SS * 256;
    const float* whh = dir ? w_hh_b : w_hh_f;
    // weights: gates g4*64+lane (unit=lane), j in [16*wv, 16*wv+16)
    v2f w2[4][8];
    #pragma unroll
    for (int g4 = 0; g4 < 4; ++g4) {
        const float* r = whh + (size_t)(g4 * 64 + lane) * 64 + 16 * wv;
        #pragma unroll
        for (int jj = 0; jj < 8; ++jj) w2[g4][jj] = v2f{r[2 * jj], r[2 * jj + 1]};
    }
    hbuf[wv][lane] = 0.f;                 // own-wave copy; in-order LDS
    float c = 0.f;
    int buf = 0;
    const int t0 = dir ? (SS - 1) : 0;
    float x0 = xw[t0 * 256 +   0 + lane];
    float x1 = xw[t0 * 256 +  64 + lane];
    float x2 = xw[t0 * 256 + 128 + lane];
    float x3 = xw[t0 * 256 + 192 + lane];
    const v2f* h2p = (const v2f*)&hbuf[wv][16 * wv];   // 8 v2f chunk
    for (int tt = 0; tt < SS; ++tt) {
        const int t = dir ? (SS - 1 - tt) : tt;
        const int tn = dir ? (t - 1) : (t + 1);
        // partial matvec on h(t-1): own-chunk broadcast reads (4 ds_read_b128)
        v2f a0 = v2f{0.f, 0.f}, a1 = v2f{0.f, 0.f}, a2 = v2f{0.f, 0.f}, a3 = v2f{0.f, 0.f};
        #pragma unroll
        for (int jj = 0; jj < 8; ++jj) {
            v2f hv = h2p[jj];
            a0 = __builtin_elementwise_fma(hv, w2[0][jj], a0);
            a1 = __builtin_elementwise_fma(hv, w2[1][jj], a1);
            a2 = __builtin_elementwise_fma(hv, w2[2][jj], a2);
            a3 = __builtin_elementwise_fma(hv, w2[3][jj], a3);
        }
        float4 pw;
        pw.x = a0.x + a0.y; pw.y = a1.x + a1.y;
        pw.z = a2.x + a2.y; pw.w = a3.x + a3.y;
        *(float4*)part[buf][wv][lane] = pw;
        // prefetch next step's xw gates (overlaps the barrier)
        float nx0 = 0.f, nx1 = 0.f, nx2 = 0.f, nx3 = 0.f;
        if (tt + 1 < SS) {
            nx0 = xw[tn * 256 +   0 + lane];
            nx1 = xw[tn * 256 +  64 + lane];
            nx2 = xw[tn * 256 + 128 + lane];
            nx3 = xw[tn * 256 + 192 + lane];
        }
        __syncthreads();
        float4 p0 = *(const float4*)part[buf][0][lane];
        float4 p1 = *(const float4*)part[buf][1][lane];
        float4 p2 = *(const float4*)part[buf][2][lane];
        float4 p3 = *(const float4*)part[buf][3][lane];
        float gi = ((p0.x + p1.x) + (p2.x + p3.x)) + x0;
        float gf = ((p0.y + p1.y) + (p2.y + p3.y)) + x1;
        float gg = ((p0.z + p1.z) + (p2.z + p3.z)) + x2;
        float go = ((p0.w + p1.w) + (p2.w + p3.w)) + x3;
        float nc = sigf(gf) * c + sigf(gi) * tanh_fast(gg);
        float nh = sigf(go) * tanh_fast(nc);
        c = nc;
        hbuf[wv][lane] = nh;              // own-wave copy; read next step
        if (wv == 0) gat_in[((size_t)b * NN + t) * DD + dir * 64 + lane] = nh;
        x0 = nx0; x1 = nx1; x2 = nx2; x3 = nx3;
        buf ^= 1;
    }
}

// ---------------------------------------------------------------------------
// GAT layer-1 projection: h1 = gat_in @ Wh[k][hd] (+ per-row f1/f2 dots).
// ---------------------------------------------------------------------------
__global__ __launch_bounds__(256) void k_p1(
    const float* __restrict__ gat_in, const float* __restrict__ gat_Wh,
    const float* __restrict__ gat_ah, int k,
    float* __restrict__ h1, float* __restrict__ f1g, float* __restrict__ f2g)
{
    __shared__ float At[64 * 68];
    __shared__ float Bt[64 * 68];
    __shared__ float sf1[64], sf2[64];
    const int tid = threadIdx.x;
    const int rt = blockIdx.x, hd = blockIdx.y;
    if (tid < 64) { sf1[tid] = 0.f; sf2[tid] = 0.f; }
    const float* W = gat_Wh + ((size_t)(k * NHEADS + hd)) * DD * 64;
    const int ty = tid >> 4, tx = tid & 15;
    const int r0 = ty * 4, c0 = tx * 4;
    float acc[4][4] = {};
    for (int ph = 0; ph < 2; ++ph) {
        __syncthreads();
        for (int idx = tid; idx < 64 * 64; idx += 256) {
            int r = idx >> 6, e = idx & 63;
            At[e * 68 + r] = gat_in[((size_t)(rt * 64 + r)) * DD + ph * 64 + e];
            Bt[e * 68 + r] = W[(size_t)(ph * 64 + e) * 64 + r];
        }
        __syncthreads();
        #pragma unroll 4
        for (int e = 0; e < 64; ++e) {
            float4 a = *(const float4*)&At[e * 68 + r0];
            float4 bv = *(const float4*)&Bt[e * 68 + c0];
            float av[4] = {a.x, a.y, a.z, a.w};
            float bb[4] = {bv.x, bv.y, bv.z, bv.w};
            #pragma unroll
            for (int i = 0; i < 4; ++i)
                #pragma unroll
                for (int j = 0; j < 4; ++j) acc[i][j] = fmaf(av[i], bb[j], acc[i][j]);
        }
    }
    const float* ah = gat_ah + (size_t)(k * NHEADS + hd) * 128;
    float a1[4], a2[4];
    #pragma unroll
    for (int j = 0; j < 4; ++j) { a1[j] = ah[c0 + j]; a2[j] = ah[64 + c0 + j]; }
    #pragma unroll
    for (int i = 0; i < 4; ++i) {
        int n = rt * 64 + r0 + i;
        float4 o = make_float4(acc[i][0], acc[i][1], acc[i][2], acc[i][3]);
        *(float4*)&h1[((size_t)n * NHEADS + hd) * 64 + c0] = o;
        float p1 = acc[i][0] * a1[0] + acc[i][1] * a1[1] + acc[i][2] * a1[2] + acc[i][3] * a1[3];
        float p2 = acc[i][0] * a2[0] + acc[i][1] * a2[1] + acc[i][2] * a2[2] + acc[i][3] * a2[3];
        atomicAdd(&sf1[r0 + i], p1);
        atomicAdd(&sf2[r0 + i], p2);
    }
    __syncthreads();
    if (tid < 64) {
        f1g[hd * BN + rt * 64 + tid] = sf1[tid];
        f2g[hd * BN + rt * 64 + tid] = sf2[tid];
    }
}

// ---------------------------------------------------------------------------
// GAT layer-1 attention (sparse).  One block per row n=(b,i); wave = head.
// 8-accumulator gather (L2-latency-bound loop: more loads in flight).
// ---------------------------------------------------------------------------
__global__ __launch_bounds__(256) void k_attn1(
    const int* __restrict__ adj, const float* __restrict__ h1,
    const float* __restrict__ f1g, const float* __restrict__ f2g,
    float* __restrict__ out1, unsigned long long* __restrict__ packed)
{
    __shared__ int   nbr[NN];
    __shared__ float ep[NHEADS][NN];
    __shared__ unsigned long long wm[12];
    __shared__ int cntS;
    const int tid = threadIdx.x, wave = tid >> 6, lane = tid & 63;
    const int n = blockIdx.x;
    const int b = n / NN;
    #pragma unroll
    for (int it = 0; it < 3; ++it) {
        int j = it * 256 + tid;
        int a = adj[(size_t)n * NN + j];
        unsigned long long m = __ballot(a > 0);
        if (lane == 0) { wm[it * 4 + wave] = m; packed[(size_t)n * 12 + it * 4 + wave] = m; }
    }
    __syncthreads();
    if (wave == 0) {
        unsigned long long m = (lane < 12) ? wm[lane] : 0ULL;
        int pc = __popcll(m);
        int inc = pc;
        #pragma unroll
        for (int d = 1; d < 16; d <<= 1) { int t = __shfl_up(inc, d); if (lane >= d) inc += t; }
        int C = __shfl(inc, 11);
        if (lane == 0) cntS = C;
        int off = inc - pc;
        while (m) {
            int bit = __builtin_ctzll(m);
            nbr[off++] = lane * 64 + bit;
            m &= m - 1;
        }
    }
    __syncthreads();
    const int C = cntS;
    const int hd = wave;
    const float f1 = f1g[hd * BN + n];
    const float* f2p = f2g + hd * BN + b * NN;
    float mx = -3.0e38f;
    for (int t = lane; t < C; t += 64) {
        float e = f1 + f2p[nbr[t]];
        e = (e >= 0.f) ? e : 0.2f * e;
        ep[hd][t] = e;
        mx = fmaxf(mx, e);
    }
    mx = wred_max(mx);
    float sum = 0.f;
    for (int t = lane; t < C; t += 64) {
        float p = __expf(ep[hd][t] - mx);
        ep[hd][t] = p;
        sum += p;
    }
    sum = wred_sum(sum);
    const float* hb = h1 + (size_t)b * NN * (NHEADS * 64) + hd * 64 + lane;
    float ac0 = 0.f, ac1 = 0.f, ac2 = 0.f, ac3 = 0.f;
    float ac4 = 0.f, ac5 = 0.f, ac6 = 0.f, ac7 = 0.f;
    int t = 0;
    for (; t + 7 < C; t += 8) {
        int j0 = nbr[t],     j1 = nbr[t + 1], j2 = nbr[t + 2], j3 = nbr[t + 3];
        int j4 = nbr[t + 4], j5 = nbr[t + 5], j6 = nbr[t + 6], j7 = nbr[t + 7];
        ac0 = fmaf(ep[hd][t],     hb[(size_t)j0 * 256], ac0);
        ac1 = fmaf(ep[hd][t + 1], hb[(size_t)j1 * 256], ac1);
        ac2 = fmaf(ep[hd][t + 2], hb[(size_t)j2 * 256], ac2);
        ac3 = fmaf(ep[hd][t + 3], hb[(size_t)j3 * 256], ac3);
        ac4 = fmaf(ep[hd][t + 4], hb[(size_t)j4 * 256], ac4);
        ac5 = fmaf(ep[hd][t + 5], hb[(size_t)j5 * 256], ac5);
        ac6 = fmaf(ep[hd][t + 6], hb[(size_t)j6 * 256], ac6);
        ac7 = fmaf(ep[hd][t + 7], hb[(size_t)j7 * 256], ac7);
    }
    for (; t < C; ++t) ac0 = fmaf(ep[hd][t], hb[(size_t)nbr[t] * 256], ac0);
    float r = (((ac0 + ac1) + (ac2 + ac3)) + ((ac4 + ac5) + (ac6 + ac7))) / sum;
    r = (r > 0.f) ? r : expm1f(r);
    out1[(size_t)n * 256 + hd * 64 + lane] = r;
}

// ---------------------------------------------------------------------------
// Output-layer projection: h2 = out1 @ Wo[k]  (+ f1o/f2o dots).  12 rows/block.
// ---------------------------------------------------------------------------
__global__ __launch_bounds__(256) void k_p2(
    const float* __restrict__ out1, const float* __restrict__ gat_Wo,
    const float* __restrict__ gat_ao, int k,
    float* __restrict__ h2, float* __restrict__ f1o, float* __restrict__ f2o)
{
    __shared__ float ld[12 * 256];
    __shared__ float lf1[12], lf2[12];
    const int tid = threadIdx.x;
    const int blk = blockIdx.x;
    if (tid < 12) { lf1[tid] = 0.f; lf2[tid] = 0.f; }
    for (int idx = tid; idx < 12 * 256; idx += 256)
        ld[idx] = out1[(size_t)blk * 12 * 256 + idx];
    __syncthreads();
    if (tid < 252) {
        const int r = tid / TT, c = tid - r * TT;
        const float* Wo = gat_Wo + (size_t)k * 256 * TT;
        const float4* row4 = (const float4*)&ld[r * 256];
        float acc = 0.f;
        #pragma unroll 8
        for (int q4 = 0; q4 < 64; ++q4) {
            float4 v = row4[q4];
            int q = q4 * 4;
            acc = fmaf(v.x, Wo[(q + 0) * TT + c], acc);
            acc = fmaf(v.y, Wo[(q + 1) * TT + c], acc);
            acc = fmaf(v.z, Wo[(q + 2) * TT + c], acc);
            acc = fmaf(v.w, Wo[(q + 3) * TT + c], acc);
        }
        const int n = blk * 12 + r;
        h2[(size_t)n * TT + c] = acc;
        const float* ao = gat_ao + k * 2 * TT;
        atomicAdd(&lf1[r], acc * ao[c]);
        atomicAdd(&lf2[r], acc * ao[TT + c]);
    }
    __syncthreads();
    if (tid < 12) {
        f1o[blk * 12 + tid] = lf1[tid];
        f2o[blk * 12 + tid] = lf2[tid];
    }
}

// ---------------------------------------------------------------------------
// Output-layer attention + elu.  One wave per (b, s<S).  Gather uses 63
// lanes = (p-part 0..2) x (tag 0..20): 3x the loads in flight / 3x fewer
// serial iterations vs the 21-lane version; partials reduced via shfl.
// ---------------------------------------------------------------------------
__global__ __launch_bounds__(64) void k_attn2(
    const unsigned long long* __restrict__ packed,
    const float* __restrict__ h2, const float* __restrict__ f1o,
    const float* __restrict__ f2o, float* __restrict__ out2k)
{
    __shared__ int   nbr[NN];
    __shared__ float ep[NN];
    const int lane = threadIdx.x;
    const int blk = blockIdx.x;                 // b*S + s
    const int b = blk / SS, s = blk - b * SS;
    const int n = b * NN + s;
    unsigned long long w64 = (lane < 12) ? packed[(size_t)n * 12 + lane] : 0ULL;
    int pc = __popcll(w64);
    int inc = pc;
    #pragma unroll
    for (int d = 1; d < 16; d <<= 1) {
        int t = __shfl_up(inc, d, 16);
        if ((lane & 15) >= d) inc += t;
    }
    const int C = __shfl(inc, 11);
    int off = inc - pc;
    while (w64) {
        int bit = __builtin_ctzll(w64);
        nbr[off++] = lane * 64 + bit;
        w64 &= w64 - 1;
    }
    __syncthreads();
    const float f1 = f1o[n];
    const float* f2p = f2o + b * NN;
    float mx = -3.0e38f;
    for (int t = lane; t < C; t += 64) {
        int j = nbr[t];
        float e = f1 + f2p[j];
        e = (e >= 0.f) ? e : 0.2f * e;
        ep[t] = e;
        mx = fmaxf(mx, e);
    }
    mx = wred_max(mx);
    float sum = 0.f;
    for (int t = lane; t < C; t += 64) {
        float p = __expf(ep[t] - mx);
        ep[t] = p;
        sum += p;
    }
    sum = wred_sum(sum);
    // gather: lane = p*21 + c  (p = neighbor-partition, c = tag); lane 63 idle
    const int p = lane / TT;                    // 0,1,2 (3 for lane 63)
    const int c = lane - p * TT;
    const bool act = (lane < 63);
    const float* h2b = h2 + (size_t)b * NN * TT + c;
    float ac0 = 0.f, ac1 = 0.f, ac2 = 0.f, ac3 = 0.f;
    if (act) {
        int t = p;
        for (; t + 9 < C; t += 12) {
            ac0 = fmaf(ep[t],     h2b[(size_t)nbr[t]     * TT], ac0);
            ac1 = fmaf(ep[t + 3], h2b[(size_t)nbr[t + 3] * TT], ac1);
            ac2 = fmaf(ep[t + 6], h2b[(size_t)nbr[t + 6] * TT], ac2);
            ac3 = fmaf(ep[t + 9], h2b[(size_t)nbr[t + 9] * TT], ac3);
        }
        for (; t < C; t += 3) ac0 = fmaf(ep[t], h2b[(size_t)nbr[t] * TT], ac0);
    }
    float ac = (ac0 + ac1) + (ac2 + ac3);
    float acB = __shfl(ac, lane + 21);
    float acC = __shfl(ac, lane + 42);
    if (lane < TT) {
        float r = (ac + acB + acC) / sum;
        r = (r > 0.f) ? r : expm1f(r);
        out2k[(size_t)blk * TT + lane] = r;
    }
}

// ---------------------------------------------------------------------------
// feats = fuse_w[0]*(lstm_feat@h2h_W^T + b) + sum_k fuse_w[k+1]*out2_k
// ---------------------------------------------------------------------------
__global__ __launch_bounds__(64) void k_fuse(
    const float* __restrict__ gat_in, const float* __restrict__ h2h_W,
    const float* __restrict__ h2h_b, const float* __restrict__ fuse_w,
    const float* __restrict__ out2, float* __restrict__ feats)
{
    __shared__ float row[DD];
    const int lane = threadIdx.x;
    const int blk = blockIdx.x;                 // b*S + s
    const int b = blk / SS, s = blk - b * SS;
    const float* src = gat_in + ((size_t)b * NN + s) * DD;
    row[lane] = src[lane];
    row[lane + 64] = src[lane + 64];
    __syncthreads();
    if (lane < TT) {
        float acc = h2h_b[lane];
        const float4* w4 = (const float4*)&h2h_W[lane * DD];
        const float4* r4 = (const float4*)row;
        #pragma unroll 8
        for (int d4 = 0; d4 < 32; ++d4) {
            float4 w = w4[d4]; float4 v = r4[d4];
            acc = fmaf(w.x, v.x, acc); acc = fmaf(w.y, v.y, acc);
            acc = fmaf(w.z, v.z, acc); acc = fmaf(w.w, v.w, acc);
        }
        size_t o = (size_t)blk * TT + lane;
        feats[o] = fuse_w[0] * acc + fuse_w[1] * out2[o]
                 + fuse_w[2] * out2[(size_t)BS * TT + o]
                 + fuse_w[3] * out2[2 * (size_t)BS * TT + o];
    }
}

// ---------------------------------------------------------------------------
// Viterbi decode.  256 threads stage feats row (32KB LDS) coalesced; wave 0
// then runs a barrier-free shfl-only scan and a pipelined shfl backtrace.
// ---------------------------------------------------------------------------
__global__ __launch_bounds__(256) void k_vit(
    const float* __restrict__ feats, const float* __restrict__ trans,
    int* __restrict__ out)
{
    __shared__ float sfeat[SS * TT];            // 8064 floats = 32.25 KB
    __shared__ unsigned char bp[(SS - 1) * 24]; // 9.2 KB
    const int tid = threadIdx.x;
    const int b = blockIdx.x;
    // stage feats[b] coalesced as float4 (8064 = 2016 float4)
    {
        const float4* src = (const float4*)(feats + (size_t)b * SS * TT);
        float4* dst = (float4*)sfeat;
        #pragma unroll
        for (int i = 0; i < 8; ++i) {
            int idx = i * 256 + tid;
            if (idx < 2016) dst[idx] = src[idx];
        }
    }
    __syncthreads();
    if (tid >= 64) return;                      // wave 0 runs the scan
    const int lane = tid;
    const int pg = lane / TT;                   // 0,1,2 (lane 63 idle)
    const int c = lane - pg * TT;
    const bool act = (pg < 3);
    const int p0 = pg * 7;
    float tc[7];
    if (act) {
        #pragma unroll
        for (int u = 0; u < 7; ++u) tc[u] = trans[(p0 + u) * TT + c];
    }
    const float tr_stop = (lane < TT) ? trans[lane * TT + 20] : 0.f;
    // part in registers on lanes 0..20
    float pp = (lane < TT) ? (sfeat[lane] + trans[19 * TT + lane]) : -3.0e38f;
    const int sfl = (lane < TT) ? lane : 0;
    for (int t = 1; t < SS; ++t) {
        float sf = sfeat[t * TT + sfl];         // off critical path
        float best = -3.0e38f; int bi = 0;
        #pragma unroll
        for (int u = 0; u < 7; ++u) {
            float pu = __shfl(pp, p0 + u);      // sources are lanes 0..20
            float v = pu + tc[u];
            if (act && v > best) { best = v; bi = p0 + u; }
        }
        float bv1 = __shfl(best, lane + 21);
        int   bi1 = __shfl(bi,   lane + 21);
        float bv2 = __shfl(best, lane + 42);
        int   bi2 = __shfl(bi,   lane + 42);
        if (lane < TT) {
            if (bv1 > best) { best = bv1; bi = bi1; }
            if (bv2 > best) { best = bv2; bi = bi2; }
            bp[(t - 1) * 24 + lane] = (unsigned char)bi;
            pp = best + sf;
        }
    }
    // final argmax (first-index tie-break)
    float fv = (lane < TT) ? pp + tr_stop : -3.0e38f;
    int fi = (lane < TT) ? lane : 0;
    #pragma unroll
    for (int o = 32; o > 0; o >>= 1) {
        float ov = __shfl_xor(fv, o);
        int oi = __shfl_xor(fi, o);
        if (ov > fv || (ov == fv && oi < fi)) { fv = ov; fi = oi; }
    }
    // pipelined backtrace: all lanes hold row u's 21 bytes; shfl picks [cur]
    int cur = fi;
    if (lane == 0) out[b * SS + SS - 1] = cur;
    int r = (lane < TT) ? (int)bp[(SS - 2) * 24 + lane] : 0;
    for (int u = SS - 2; u >= 0; --u) {
        int rn = 0;
        if (u > 0 && lane < TT) rn = (int)bp[(u - 1) * 24 + lane];  // prefetch
        cur = __shfl(r, cur);
        if (lane == 0) out[b * SS + u] = cur;
        r = rn;
    }
}

// ---------------------------------------------------------------------------
extern "C" void kernel_launch(void* const* d_in, const int* in_sizes, int n_in,
                              void* d_out, int out_size, void* d_ws, size_t ws_size,
                              hipStream_t stream) {
    (void)in_sizes; (void)n_in; (void)out_size; (void)ws_size;
    const int*   batch_char = (const int*)d_in[0];
    const int*   gaz_list   = (const int*)d_in[2];
    const int*   graphs[3]  = {(const int*)d_in[3], (const int*)d_in[4], (const int*)d_in[5]};
    const float* char_table = (const float*)d_in[7];
    const float* gaz_table  = (const float*)d_in[8];
    const float* w_ih_f = (const float*)d_in[9];
    const float* w_hh_f = (const float*)d_in[10];
    const float* b_f    = (const float*)d_in[11];
    const float* w_ih_b = (const float*)d_in[12];
    const float* w_hh_b = (const float*)d_in[13];
    const float* b_b    = (const float*)d_in[14];
    const float* h2h_W  = (const float*)d_in[15];
    const float* h2h_b  = (const float*)d_in[16];
    const float* gat_Wh = (const float*)d_in[17];
    const float* gat_ah = (const float*)d_in[18];
    const float* gat_Wo = (const float*)d_in[19];
    const float* gat_ao = (const float*)d_in[20];
    const float* fuse_w = (const float*)d_in[21];
    const float* trans  = (const float*)d_in[22];

    float* ws = (float*)d_ws;
    float* gat_in = ws;                         // 1,572,864
    float* xw_f   = gat_in + 1572864;           // 1,572,864
    float* xw_b   = xw_f   + 1572864;           // 1,572,864
    float* h1     = xw_b   + 1572864;           // 3,145,728
    float* out1   = h1     + 3145728;           // 3,145,728
    float* h2     = out1   + 3145728;           //   258,048
    float* f1g    = h2     + 258048;            //    49,152
    float* f2g    = f1g    + 49152;             //    49,152
    float* f1o    = f2g    + 49152;             //    12,288
    float* f2o    = f1o    + 12288;             //    12,288
    float* out2   = f2o    + 12288;             //   387,072
    float* feats  = out2   + 387072;            //   129,024
    unsigned long long* packed = (unsigned long long*)(feats + 129024);  // 98,304 u64

    k_xw<<<dim3(96, 8), 256, 0, stream>>>(batch_char, char_table, w_ih_f, b_f,
                                          w_ih_b, b_b, xw_f, xw_b);
    k_gaz<<<3072, 256, 0, stream>>>(gaz_list, gaz_table, gat_in);
    k_lstm<<<32, 256, 0, stream>>>(xw_f, xw_b, w_hh_f, w_hh_b, gat_in);
    for (int k = 0; k < 3; ++k) {
        k_p1<<<dim3(192, 4), 256, 0, stream>>>(gat_in, gat_Wh, gat_ah, k, h1, f1g, f2g);
        k_attn1<<<BN, 256, 0, stream>>>(graphs[k], h1, f1g, f2g, out1, packed);
        k_p2<<<1024, 256, 0, stream>>>(out1, gat_Wo, gat_ao, k, h2, f1o, f2o);
        k_attn2<<<BS, 64, 0, stream>>>(packed, h2, f1o, f2o, out2 + (size_t)k * BS * TT);
    }
    k_fuse<<<BS, 64, 0, stream>>>(gat_in, h2h_W, h2h_b, fuse_w, out2, feats);
    k_vit<<<BB, 256, 0, stream>>>(feats, trans, (int*)d_out);
}